// Round 26
// baseline (4288.686 us; speedup 1.0000x reference)
//
#include <hip/hip_runtime.h>

typedef unsigned long long u64;
typedef unsigned int u32;

#define CONF 0.05f

__device__ __forceinline__ u32 fmono(float f) {
  u32 u = __float_as_uint(f);
  return (u & 0x80000000u) ? ~u : (u | 0x80000000u);
}

// plain-form f32 sigmoid: 1/(1+exp(-x)), exp correctly rounded via f64.
__device__ __forceinline__ float sig32(float x) {
  float e = (float)exp(-(double)x);
  return 1.0f / __fadd_rn(1.0f, e);
}

// ------------- weight transpose: w[(g*8+co)*2304 + k] -> wT[((g*2304)+k)*8+co]
__global__ __launch_bounds__(256) void wtrans(const float* __restrict__ w,
                                              float* __restrict__ wT, int n)
{
  int idx = blockIdx.x*256 + threadIdx.x;
  if (idx >= n) return;
  int co = idx & 7;
  int r  = idx >> 3;            // (l*32+g)*2304 + k
  int k  = r % 2304;
  int lg = r / 2304;            // l*32+g
  int g  = lg & 31;
  int l  = lg >> 5;
  wT[idx] = w[(size_t)l*589824 + (size_t)(g*8+co)*2304 + k];
}

// ---------------- conv 3x3 + bias + relu (both towers, one layer) ----------
// PER-TAP numpy-conv tree (verified round 12): per tap sequential FMA chain
// over cin 0..255 ascending; taps combined by 8 separate f32 adds row-major;
// separate f32 bias add; relu. Tile 32x8, 8 couts. ASYNC staging of BOTH
// input AND weights via global_load_lds (double-buffered LDS, one barrier
// per stage) -- weights read as wave-uniform broadcast ds_read_b128 instead
// of per-cin s_load chains (removes exposed scalar-load latency).
#define CIN_T 8

__global__ __launch_bounds__(256) void conv_all(
    const float* __restrict__ inc0, const float* __restrict__ inc1, const float* __restrict__ inc2,
    const float* __restrict__ inr0, const float* __restrict__ inr1, const float* __restrict__ inr2,
    float* __restrict__ outc0, float* __restrict__ outc1, float* __restrict__ outc2,
    float* __restrict__ outr0, float* __restrict__ outr1, float* __restrict__ outr2,
    const float* __restrict__ wTc, const float* __restrict__ wTr,
    const float* __restrict__ bc, const float* __restrict__ br,
    const float* __restrict__ zbuf)
{
  __shared__ float s_in[2][CIN_T][404];
  __shared__ __align__(16) float s_w[2][CIN_T*72];
  int b = blockIdx.x;
  int tower = (b >= 2688) ? 1 : 0;
  int bb0 = b - (tower ? 2688 : 0);
  int lvl, tile, cog;
  if (bb0 < 2048)      { lvl = 0; cog = bb0 >> 6;                  tile = bb0 & 63; }
  else if (bb0 < 2560) { lvl = 1; int bb = bb0-2048; cog = bb >> 4; tile = bb & 15; }
  else                 { lvl = 2; int bb = bb0-2560; cog = bb >> 2; tile = bb & 3; }
  const int H  = (lvl==0) ? 128 : (lvl==1) ? 64 : 32;
  const int HW = H*H;
  const float* in = tower ? ((lvl==0)?inr0:(lvl==1)?inr1:inr2)
                          : ((lvl==0)?inc0:(lvl==1)?inc1:inc2);
  float* out     = tower ? ((lvl==0)?outr0:(lvl==1)?outr1:outr2)
                         : ((lvl==0)?outc0:(lvl==1)?outc1:outc2);
  const float* wT   = tower ? wTr : wTc;
  const float* bias = tower ? br  : bc;
  int tilesW = H >> 5;                 // tiles of 32 in x
  int tx = (tile % tilesW) << 5;
  int ty = (tile / tilesW) << 3;       // tiles of 8 in y
  int cob = cog << 3;
  const float* wTg = wT + (size_t)cog * 18432;   // 2304*8 per group
  int t = threadIdx.x;
  int py = t >> 5;          // 0..7
  int px = t & 31;          // 0..31

  // hoisted staging decomposition: slot A = t (all threads), slot B = t+256
  // (only waves 0,1: t<128 -> t2 in 256..383, LDS slot <= 383 < 404)
  int r1 = t / 34, c1 = t - r1*34;
  int iy1 = ty - 1 + r1, ix1 = tx - 1 + c1;
  bool v1 = (iy1 >= 0 && iy1 < H && ix1 >= 0 && ix1 < H);
  int t2 = t + 256;
  int r2 = t2 / 34, c2 = t2 - r2*34;
  int iy2 = ty - 1 + r2, ix2 = tx - 1 + c2;
  bool v2 = (t2 < 340) && (iy2 >= 0 && iy2 < H && ix2 >= 0 && ix2 < H);

  const char* cur1 = v1 ? (const char*)(in + iy1*H + ix1) : (const char*)zbuf;
  const char* cur2 = v2 ? (const char*)(in + iy2*H + ix2) : (const char*)zbuf;
  size_t st1 = v1 ? (size_t)HW*4 : 0;
  size_t st2 = v2 ? (size_t)HW*4 : 0;

// stage input tile (as r21) AND this stage's 576 weight floats (contiguous)
#define ISSUE(BUF, CB)                                                \
  {                                                                   \
    _Pragma("unroll")                                                 \
    for (int ci = 0; ci < CIN_T; ++ci) {                              \
      __builtin_amdgcn_global_load_lds(                               \
          (const unsigned int*)cur1,                                  \
          (unsigned int*)&s_in[BUF][ci][t], 4, 0, 0);                 \
      if (t < 128)                                                    \
        __builtin_amdgcn_global_load_lds(                             \
            (const unsigned int*)cur2,                                \
            (unsigned int*)&s_in[BUF][ci][t2], 4, 0, 0);              \
      cur1 += st1; cur2 += st2;                                       \
    }                                                                 \
    const float* wsrc = wTg + (size_t)(CB) * 72;                      \
    __builtin_amdgcn_global_load_lds(                                 \
        (const unsigned int*)(wsrc + t),                              \
        (unsigned int*)&s_w[BUF][t], 4, 0, 0);                        \
    __builtin_amdgcn_global_load_lds(                                 \
        (const unsigned int*)(wsrc + t + 256),                        \
        (unsigned int*)&s_w[BUF][t + 256], 4, 0, 0);                  \
    if (t < 64)                                                       \
      __builtin_amdgcn_global_load_lds(                               \
          (const unsigned int*)(wsrc + t + 512),                      \
          (unsigned int*)&s_w[BUF][t + 512], 4, 0, 0);                \
  }

  float acc[9][8];          // per-tap partial chains (registers)
  #pragma unroll
  for (int tp = 0; tp < 9; ++tp)
    #pragma unroll
    for (int c = 0; c < 8; ++c) acc[tp][c] = 0.f;

  ISSUE(0, 0)
  int buf = 0;
  #pragma unroll 1
  for (int cb = 0; cb < 256; cb += CIN_T) {
    __syncthreads();                 // drains async loads into buf
    if (cb + CIN_T < 256) ISSUE(buf^1, cb + CIN_T)   // prefetch next stage
    // per-tap sequential FMA chains, cin ascending; weights via LDS broadcast
    #pragma unroll 1
    for (int cin = 0; cin < CIN_T; ++cin) {
      const float* wp = &s_w[buf][cin*72];
      float v[9];
      #pragma unroll
      for (int ky = 0; ky < 3; ++ky)
        #pragma unroll
        for (int kx = 0; kx < 3; ++kx)
          v[ky*3+kx] = s_in[buf][cin][(py+ky)*34 + px + kx];
      #pragma unroll
      for (int tp = 0; tp < 9; ++tp) {
        #pragma unroll
        for (int c = 0; c < 8; ++c)
          acc[tp][c] = __builtin_fmaf(v[tp], wp[tp*8+c], acc[tp][c]);
      }
    }
    buf ^= 1;
  }
#undef ISSUE
  // combine taps: row-major order, separate f32 adds; then bias, relu
  int y = ty + py, x0 = tx + px;
  #pragma unroll
  for (int c = 0; c < 8; ++c) {
    float tot = acc[0][c];
    #pragma unroll
    for (int tp = 1; tp < 9; ++tp) tot = __fadd_rn(tot, acc[tp][c]);
    tot = __fadd_rn(tot, bias[cob+c]);
    out[(size_t)(cob+c)*HW + y*H + x0] = fmaxf(tot, 0.f);
  }
}

// ------- 1x1 heads: k=256 single sequential FMA chain (verified) -----------
__global__ __launch_bounds__(256) void head_decode(
    const float* __restrict__ cfB, const float* __restrict__ rfC,
    const float* __restrict__ w_cls, const float* __restrict__ b_cls,
    const float* __restrict__ w_reg, const float* __restrict__ b_reg,
    const float* __restrict__ w_ctn, const float* __restrict__ b_ctn,
    float* __restrict__ score_all, int* __restrict__ label_all,
    float* __restrict__ box_all, u64* __restrict__ keys)
{
  __shared__ float s_ct[64];
  __shared__ float s_v[4][64];
  __shared__ int   s_i[4][64];
  int b = blockIdx.x;
  int lvl, lb;
  if (b < 256)      { lvl = 0; lb = b; }
  else if (b < 320) { lvl = 1; lb = b - 256; }
  else              { lvl = 2; lb = b - 320; }
  const int H  = (lvl==0)?128:(lvl==1)?64:32;
  const int HW = H*H;
  const int loff = (lvl==0)?0:(lvl==1)?16384:20480;
  const size_t foff = (lvl==0)?0:(lvl==1)?4194304:5242880;
  const float strd = (lvl==0)?8.f:(lvl==1)?16.f:32.f;
  const float* cf = cfB + foff;
  const float* rf = rfC + foff;
  int lane = threadIdx.x & 63;
  int wv = __builtin_amdgcn_readfirstlane((int)(threadIdx.x >> 6));  // SGPR
  int pix = lb*64 + lane;

  float lg[20];
  #pragma unroll
  for (int k = 0; k < 20; ++k) lg[k] = 0.f;
  float rg0 = 0.f, rg1 = 0.f, rg2 = 0.f, rg3 = 0.f, ct = 0.f;

  for (int c = 0; c < 256; ++c) {
    float fv = cf[(size_t)c*HW + pix];
    #pragma unroll
    for (int k = 0; k < 20; ++k)
      lg[k] = __builtin_fmaf(fv, w_cls[(wv*20+k)*256 + c], lg[k]);
    if (wv == 0) {
      float rv = rf[(size_t)c*HW + pix];
      rg0 = __builtin_fmaf(rv, w_reg[      c], rg0);
      rg1 = __builtin_fmaf(rv, w_reg[256 + c], rg1);
      rg2 = __builtin_fmaf(rv, w_reg[512 + c], rg2);
      rg3 = __builtin_fmaf(rv, w_reg[768 + c], rg3);
      ct  = __builtin_fmaf(rv, w_ctn[      c], ct);
    }
  }
  if (wv == 0) s_ct[lane] = __fadd_rn(ct, b_ctn[0]);
  __syncthreads();
  float sig_t = sig32(s_ct[lane]);

  // per-class f32 score, argmax with first-index tie-break
  float bsc = -1.f; int bk = 0;
  #pragma unroll
  for (int k = 0; k < 20; ++k) {
    float l32 = __fadd_rn(lg[k], b_cls[wv*20 + k]);
    float scv = sqrtf(__fmul_rn(sig32(l32), sig_t));
    if (scv > bsc) { bsc = scv; bk = wv*20 + k; }
  }
  s_v[wv][lane] = bsc;
  s_i[wv][lane] = bk;
  __syncthreads();
  if (wv != 0) return;
  #pragma unroll
  for (int g = 1; g < 4; ++g) {
    float v = s_v[g][lane];
    if (v > bsc) { bsc = v; bk = s_i[g][lane]; }
  }
  rg0 = __fadd_rn(rg0, b_reg[0]); rg1 = __fadd_rn(rg1, b_reg[1]);
  rg2 = __fadd_rn(rg2, b_reg[2]); rg3 = __fadd_rn(rg3, b_reg[3]);
  int yq = pix / H;
  int xq = pix - yq*H;
  float ax = (float)xq + 0.5f, ay = (float)yq + 0.5f;
  float e0 = (float)exp((double)rg0), e1 = (float)exp((double)rg1);
  float e2 = (float)exp((double)rg2), e3 = (float)exp((double)rg3);
  float scl = strd * (1.0f/1024.0f);
  float bx1 = fminf(fmaxf(__fmul_rn(__fadd_rn(ax, -e0), scl), 0.f), 1.f);
  float by1 = fminf(fmaxf(__fmul_rn(__fadd_rn(ay, -e1), scl), 0.f), 1.f);
  float bx2 = fminf(fmaxf(__fmul_rn(__fadd_rn(ax,  e2), scl), 0.f), 1.f);
  float by2 = fminf(fmaxf(__fmul_rn(__fadd_rn(ay,  e3), scl), 0.f), 1.f);
  int gi = loff + pix;
  score_all[gi] = bsc;
  label_all[gi] = bk;
  box_all[gi*4+0] = bx1; box_all[gi*4+1] = by1;
  box_all[gi*4+2] = bx2; box_all[gi*4+3] = by2;
  keys[gi] = ((u64)fmono(bsc) << 32) | (u64)(0xFFFFFFFFu - (u32)pix);
}

// ---------------- bitonic sort (descending, u64 keys) ----------------------
__global__ __launch_bounds__(256) void sort_local(u64* __restrict__ keys)
{
  __shared__ u64 s[2048];
  int t = threadIdx.x;
  int base = blockIdx.x * 2048;
  #pragma unroll
  for (int r = 0; r < 8; ++r) s[t + r*256] = keys[base + t + r*256];
  __syncthreads();
  for (int k = 2; k <= 2048; k <<= 1) {
    for (int j = k >> 1; j >= 1; j >>= 1) {
      #pragma unroll
      for (int r = 0; r < 4; ++r) {
        int p = t + r*256;
        int i = ((p & ~(j-1)) << 1) | (p & (j-1));
        bool asc = (((base + i) & k) != 0);
        u64 a = s[i], b2 = s[i|j];
        if (asc ? (a > b2) : (a < b2)) { s[i] = b2; s[i|j] = a; }
      }
      __syncthreads();
    }
  }
  #pragma unroll
  for (int r = 0; r < 8; ++r) keys[base + t + r*256] = s[t + r*256];
}

__global__ void sort_global_pass(u64* __restrict__ keys, int j, int k, int P)
{
  int p = blockIdx.x*256 + threadIdx.x;
  if (p >= (P >> 1)) return;
  int i = ((p & ~(j-1)) << 1) | (p & (j-1));
  int l = i | j;
  bool asc = ((i & k) != 0);
  u64 a = keys[i], b = keys[l];
  if (asc ? (a > b) : (a < b)) { keys[i] = b; keys[l] = a; }
}

__global__ __launch_bounds__(256) void sort_local_finish(u64* __restrict__ keys, int k)
{
  __shared__ u64 s[2048];
  int t = threadIdx.x;
  int base = blockIdx.x * 2048;
  #pragma unroll
  for (int r = 0; r < 8; ++r) s[t + r*256] = keys[base + t + r*256];
  __syncthreads();
  for (int j = 1024; j >= 1; j >>= 1) {
    #pragma unroll
    for (int r = 0; r < 4; ++r) {
      int p = t + r*256;
      int i = ((p & ~(j-1)) << 1) | (p & (j-1));
      bool asc = (((base + i) & k) != 0);
      u64 a = s[i], b2 = s[i|j];
      if (asc ? (a > b2) : (a < b2)) { s[i] = b2; s[i|j] = a; }
    }
    __syncthreads();
  }
  #pragma unroll
  for (int r = 0; r < 8; ++r) keys[base + t + r*256] = s[t + r*256];
}

__global__ void zero_keys(u64* __restrict__ keys, int n) {
  int i = blockIdx.x*256 + threadIdx.x;
  if (i < n) keys[i] = 0ull;
}

// ---------------- gather per-level top-1000 --------------------------------
__global__ void gather_top(const u64* __restrict__ keys,
    const float* __restrict__ score_all, const int* __restrict__ label_all,
    const float* __restrict__ box_all, int loff, int lvl,
    float* __restrict__ out, float* __restrict__ s3k, int* __restrict__ l3k,
    float* __restrict__ b3k)
{
  int r = blockIdx.x*256 + threadIdx.x;
  if (r >= 1000) return;
  u64 key = keys[r];
  u32 pix = 0xFFFFFFFFu - (u32)(key & 0xFFFFFFFFull);
  int gi = loff + (int)pix;
  int g = lvl*1000 + r;
  float sc = score_all[gi];
  int lb = label_all[gi];
  s3k[g] = sc; l3k[g] = lb;
  out[12000 + g] = sc;
  out[15000 + g] = (float)lb;
  #pragma unroll
  for (int c = 0; c < 4; ++c) {
    float v = box_all[gi*4 + c];
    b3k[g*4+c] = v;
    out[g*4+c] = v;
  }
}

// ---------------- NMS ------------------------------------------------------
__global__ void nms_pack(const float* __restrict__ s3k, u64* __restrict__ nkeys) {
  int r = blockIdx.x*256 + threadIdx.x;
  if (r >= 4096) return;
  nkeys[r] = (r < 3000)
      ? (((u64)fmono(s3k[r]) << 32) | (u64)(0xFFFFFFFFu - (u32)r))
      : 0ull;
}

__global__ void nms_gather(const u64* __restrict__ nkeys,
    const float* __restrict__ s3k, const int* __restrict__ l3k, const float* __restrict__ b3k,
    float* __restrict__ bs, int* __restrict__ ls, int* __restrict__ order,
    float* __restrict__ ss)
{
  int i = blockIdx.x*256 + threadIdx.x;
  if (i >= 3000) return;
  u64 key = nkeys[i];
  u32 r = 0xFFFFFFFFu - (u32)(key & 0xFFFFFFFFull);
  order[i] = (int)r;
  ss[i] = s3k[r];
  ls[i] = l3k[r];
  #pragma unroll
  for (int c = 0; c < 4; ++c) bs[i*4+c] = b3k[(int)r*4+c];
}

__global__ void nms_supp(const float* __restrict__ bs, const int* __restrict__ ls,
                         u64* __restrict__ supp)
{
  int id = blockIdx.x*256 + threadIdx.x;
  if (id >= 3000*47) return;
  int i = id / 47, w = id - (id/47)*47;
  float x1 = bs[i*4+0], y1 = bs[i*4+1], x2 = bs[i*4+2], y2 = bs[i*4+3];
  float ai = (x2-x1)*(y2-y1);
  int li = ls[i];
  u64 m = 0;
  int j0 = w*64;
  #pragma unroll 1
  for (int bb = 0; bb < 64; ++bb) {
    int j = j0 + bb;
    if (j >= 3000) break;
    if (j <= i || ls[j] != li) continue;
    float xj1 = bs[j*4+0], yj1 = bs[j*4+1], xj2 = bs[j*4+2], yj2 = bs[j*4+3];
    float aj = (xj2-xj1)*(yj2-yj1);
    float xx1 = fmaxf(x1, xj1), yy1 = fmaxf(y1, yj1);
    float xx2 = fminf(x2, xj2), yy2 = fminf(y2, yj2);
    float inter = fmaxf(1e-28f, xx2-xx1) * fmaxf(1e-28f, yy2-yy1);
    float iou = inter / (ai + aj - inter + 1e-14f);
    if (iou > 0.6f) m |= (1ull << bb);
  }
  supp[(size_t)i*47 + w] = m;
}

// serial greedy scan, latency-hidden: depth-64 register prefetch ring +
// scalar (readlane) current-word bit test. One wave. (r14 version, verified)
__global__ __launch_bounds__(64) void nms_seq(const u64* __restrict__ supp,
    const float* __restrict__ ss, const int* __restrict__ order,
    float* __restrict__ out)
{
  int lane = threadIdx.x;  // 64 threads, one wave
  bool active = lane < 47;
  u64 kw = 0;
  if (active) {
    for (int bb = 0; bb < 64; ++bb) {
      int i = lane*64 + bb;
      if (i < 3000 && ss[i] >= CONF) kw |= (1ull << bb);
    }
  }
  u64 ring[64];
  #pragma unroll
  for (int d = 0; d < 64; ++d)
    ring[d] = active ? supp[(size_t)d*47 + lane] : 0ull;

  #pragma unroll 1
  for (int blk = 0; blk < 47; ++blk) {
    #pragma unroll
    for (int d = 0; d < 64; ++d) {
      u32 half = (d < 32)
          ? __builtin_amdgcn_readlane((u32)kw, blk)
          : __builtin_amdgcn_readlane((u32)(kw >> 32), blk);
      if ((half >> (d & 31)) & 1u)
        kw &= ~ring[d];
      int nr = (blk + 1) * 64 + d;
      ring[d] = (active && nr < 3008) ? supp[(size_t)nr*47 + lane] : 0ull;
    }
  }
  if (active) {
    for (int bb = 0; bb < 64; ++bb) {
      int i = lane*64 + bb;
      if (i < 3000) out[18000 + order[i]] = ((kw >> bb) & 1ull) ? 1.0f : 0.0f;
    }
  }
}

// ---------------- host -----------------------------------------------------
extern "C" void kernel_launch(void* const* d_in, const int* in_sizes, int n_in,
                              void* d_out, int out_size, void* d_ws, size_t ws_size,
                              hipStream_t stream)
{
  const float* p3    = (const float*)d_in[0];
  const float* p4    = (const float*)d_in[1];
  const float* p5    = (const float*)d_in[2];
  const float* cls_w = (const float*)d_in[3];
  const float* cls_b = (const float*)d_in[4];
  const float* reg_w = (const float*)d_in[5];
  const float* reg_b = (const float*)d_in[6];
  const float* w_cls = (const float*)d_in[7];
  const float* b_cls = (const float*)d_in[8];
  const float* w_reg = (const float*)d_in[9];
  const float* b_reg = (const float*)d_in[10];
  const float* w_ctn = (const float*)d_in[11];
  const float* b_ctn = (const float*)d_in[12];
  float* out = (float*)d_out;

  char* wsb = (char*)d_ws;
  size_t off = 0;
  auto alloc = [&](size_t bytes) -> void* {
    void* p = wsb + off;
    off = (off + bytes + 255) & ~(size_t)255;
    return p;
  };
  const size_t SLAB = 5505024;  // floats: 256*(16384+4096+1024)
  float* A = (float*)alloc(SLAB*4);
  float* B = (float*)alloc(SLAB*4);
  float* C = (float*)alloc(SLAB*4);
  float* D = (float*)alloc(SLAB*4);
  float* wT_cls = (float*)alloc((size_t)2359296*4);
  float* wT_reg = (float*)alloc((size_t)2359296*4);
  float* zbuf = (float*)alloc(2048);
  float* score_all = (float*)alloc(21504*4);
  int*   label_all = (int*)alloc(21504*4);
  float* box_all   = (float*)alloc(21504*16);
  u64*   keys      = (u64*)alloc(22528*8);
  float* s3k  = (float*)alloc(3000*4);
  int*   l3k  = (int*)alloc(3000*4);
  float* b3k  = (float*)alloc(12000*4);
  u64*   nkeys = (u64*)alloc(4096*8);
  float* bs   = (float*)alloc(12000*4);
  int*   ls   = (int*)alloc(3000*4);
  int*   order= (int*)alloc(3000*4);
  float* ss   = (float*)alloc(3000*4);
  u64*   supp = (u64*)alloc((size_t)141376*8);  // 3008 rows x 47 (ring pad)

  const size_t F1 = 4194304, F2 = 5242880;
  const size_t WTL = 589824;  // per-layer transposed-weight float count

  // zero the async-staging clamp buffer, then pre-transpose weights
  zero_keys<<<dim3(1), dim3(256), 0, stream>>>((u64*)zbuf, 256);
  wtrans<<<dim3(9216), dim3(256), 0, stream>>>(cls_w, wT_cls, 2359296);
  wtrans<<<dim3(9216), dim3(256), 0, stream>>>(reg_w, wT_reg, 2359296);

  // merged dual-tower conv dispatches (4 layers, 5376 blocks each)
  auto CV2 = [&](const float* ic, const float* ir, float* oc, float* orr,
                 int layer) {
    conv_all<<<dim3(5376), dim3(256), 0, stream>>>(
        ic, ic+F1, ic+F2, ir, ir+F1, ir+F2,
        oc, oc+F1, oc+F2, orr, orr+F1, orr+F2,
        wT_cls + layer*WTL, wT_reg + layer*WTL,
        cls_b + layer*256, reg_b + layer*256, zbuf);
  };
  // layer 0 reads the raw pyramid (non-contiguous p3/p4/p5)
  conv_all<<<dim3(5376), dim3(256), 0, stream>>>(
      p3, p4, p5, p3, p4, p5,
      A, A+F1, A+F2, C, C+F1, C+F2,
      wT_cls, wT_reg, cls_b, reg_b, zbuf);
  CV2(A, C, B, D, 1);
  CV2(B, D, A, C, 2);
  CV2(A, C, B, D, 3);
  // cf = B, rf = D

  zero_keys<<<dim3(4), dim3(256), 0, stream>>>(keys + 21504, 1024);
  head_decode<<<dim3(336), dim3(256), 0, stream>>>(B, D, w_cls, b_cls, w_reg, b_reg,
      w_ctn, b_ctn, score_all, label_all, box_all, keys);

  auto sortP = [&](u64* k0, int P) {
    sort_local<<<dim3(P/2048), dim3(256), 0, stream>>>(k0);
    for (int k = 4096; k <= P; k <<= 1) {
      for (int j = k >> 1; j >= 2048; j >>= 1)
        sort_global_pass<<<dim3((P/2 + 255)/256), dim3(256), 0, stream>>>(k0, j, k, P);
      sort_local_finish<<<dim3(P/2048), dim3(256), 0, stream>>>(k0, k);
    }
  };
  sortP(keys,        16384);
  sortP(keys+16384,  4096);
  sortP(keys+20480,  2048);

  const int LOFF[3] = {0, 16384, 20480};
  for (int lvl = 0; lvl < 3; ++lvl)
    gather_top<<<dim3(4), dim3(256), 0, stream>>>(keys + LOFF[lvl], score_all,
        label_all, box_all, LOFF[lvl], lvl, out, s3k, l3k, b3k);

  nms_pack<<<dim3(16), dim3(256), 0, stream>>>(s3k, nkeys);
  sortP(nkeys, 4096);
  nms_gather<<<dim3(12), dim3(256), 0, stream>>>(nkeys, s3k, l3k, b3k, bs, ls, order, ss);
  nms_supp<<<dim3((3000*47 + 255)/256), dim3(256), 0, stream>>>(bs, ls, supp);
  nms_seq<<<dim3(1), dim3(64), 0, stream>>>(supp, ss, order, out);
}

// Round 27
// 3162.775 us; speedup vs baseline: 1.3560x; 1.3560x over previous
//
#include <hip/hip_runtime.h>

typedef unsigned long long u64;
typedef unsigned int u32;

#define CONF 0.05f

__device__ __forceinline__ u32 fmono(float f) {
  u32 u = __float_as_uint(f);
  return (u & 0x80000000u) ? ~u : (u | 0x80000000u);
}

// plain-form f32 sigmoid: 1/(1+exp(-x)), exp correctly rounded via f64.
__device__ __forceinline__ float sig32(float x) {
  float e = (float)exp(-(double)x);
  return 1.0f / __fadd_rn(1.0f, e);
}

// ------------- weight transpose: w[(g*8+co)*2304 + k] -> wT[((g*2304)+k)*8+co]
__global__ __launch_bounds__(256) void wtrans(const float* __restrict__ w,
                                              float* __restrict__ wT, int n)
{
  int idx = blockIdx.x*256 + threadIdx.x;
  if (idx >= n) return;
  int co = idx & 7;
  int r  = idx >> 3;            // (l*32+g)*2304 + k
  int k  = r % 2304;
  int lg = r / 2304;            // l*32+g
  int g  = lg & 31;
  int l  = lg >> 5;
  wT[idx] = w[(size_t)l*589824 + (size_t)(g*8+co)*2304 + k];
}

// ---------------- conv 3x3 + bias + relu (both towers, one layer) ----------
// PER-TAP numpy-conv tree (verified round 12): per tap sequential FMA chain
// over cin 0..255 ascending; taps combined by 8 separate f32 adds row-major;
// separate f32 bias add; relu. Scalar-path weights (72/cin chunk, 8 couts).
// Tile 32x8. ASYNC input staging via global_load_lds, double-buffered LDS,
// ONE barrier per stage; halo lanes clamp to zbuf. (r25 config — best.)
#define CIN_T 8

__global__ __launch_bounds__(256) void conv_all(
    const float* __restrict__ inc0, const float* __restrict__ inc1, const float* __restrict__ inc2,
    const float* __restrict__ inr0, const float* __restrict__ inr1, const float* __restrict__ inr2,
    float* __restrict__ outc0, float* __restrict__ outc1, float* __restrict__ outc2,
    float* __restrict__ outr0, float* __restrict__ outr1, float* __restrict__ outr2,
    const float* __restrict__ wTc, const float* __restrict__ wTr,
    const float* __restrict__ bc, const float* __restrict__ br,
    const float* __restrict__ zbuf)
{
  __shared__ float s_in[2][CIN_T][404];
  int b = blockIdx.x;
  int tower = (b >= 2688) ? 1 : 0;
  int bb0 = b - (tower ? 2688 : 0);
  int lvl, tile, cog;
  if (bb0 < 2048)      { lvl = 0; cog = bb0 >> 6;                  tile = bb0 & 63; }
  else if (bb0 < 2560) { lvl = 1; int bb = bb0-2048; cog = bb >> 4; tile = bb & 15; }
  else                 { lvl = 2; int bb = bb0-2560; cog = bb >> 2; tile = bb & 3; }
  const int H  = (lvl==0) ? 128 : (lvl==1) ? 64 : 32;
  const int HW = H*H;
  const float* in = tower ? ((lvl==0)?inr0:(lvl==1)?inr1:inr2)
                          : ((lvl==0)?inc0:(lvl==1)?inc1:inc2);
  float* out     = tower ? ((lvl==0)?outr0:(lvl==1)?outr1:outr2)
                         : ((lvl==0)?outc0:(lvl==1)?outc1:outc2);
  const float* wT   = tower ? wTr : wTc;
  const float* bias = tower ? br  : bc;
  int tilesW = H >> 5;                 // tiles of 32 in x
  int tx = (tile % tilesW) << 5;
  int ty = (tile / tilesW) << 3;       // tiles of 8 in y
  int cob = cog << 3;
  const float* wTg = wT + (size_t)cog * 18432;   // 2304*8 per group
  int t = threadIdx.x;
  int py = t >> 5;          // 0..7
  int px = t & 31;          // 0..31

  // hoisted staging decomposition: slot A = t (all threads), slot B = t+256
  // (only waves 0,1: t<128 -> t2 in 256..383, LDS slot <= 383 < 404)
  int r1 = t / 34, c1 = t - r1*34;
  int iy1 = ty - 1 + r1, ix1 = tx - 1 + c1;
  bool v1 = (iy1 >= 0 && iy1 < H && ix1 >= 0 && ix1 < H);
  int t2 = t + 256;
  int r2 = t2 / 34, c2 = t2 - r2*34;
  int iy2 = ty - 1 + r2, ix2 = tx - 1 + c2;
  bool v2 = (t2 < 340) && (iy2 >= 0 && iy2 < H && ix2 >= 0 && ix2 < H);

  const char* cur1 = v1 ? (const char*)(in + iy1*H + ix1) : (const char*)zbuf;
  const char* cur2 = v2 ? (const char*)(in + iy2*H + ix2) : (const char*)zbuf;
  size_t st1 = v1 ? (size_t)HW*4 : 0;
  size_t st2 = v2 ? (size_t)HW*4 : 0;

#define ISSUE(BUF)                                                    \
  {                                                                   \
    _Pragma("unroll")                                                 \
    for (int ci = 0; ci < CIN_T; ++ci) {                              \
      __builtin_amdgcn_global_load_lds(                               \
          (const unsigned int*)cur1,                                  \
          (unsigned int*)&s_in[BUF][ci][t], 4, 0, 0);                 \
      if (t < 128)                                                    \
        __builtin_amdgcn_global_load_lds(                             \
            (const unsigned int*)cur2,                                \
            (unsigned int*)&s_in[BUF][ci][t2], 4, 0, 0);              \
      cur1 += st1; cur2 += st2;                                       \
    }                                                                 \
  }

  float acc[9][8];          // per-tap partial chains (registers)
  #pragma unroll
  for (int tp = 0; tp < 9; ++tp)
    #pragma unroll
    for (int c = 0; c < 8; ++c) acc[tp][c] = 0.f;

  ISSUE(0)
  int buf = 0;
  #pragma unroll 1
  for (int cb = 0; cb < 256; cb += CIN_T) {
    __syncthreads();                 // drains async loads into s_in[buf]
    if (cb + CIN_T < 256) ISSUE(buf^1)   // prefetch next stage (async DMA)
    // per-tap sequential FMA chains, cin ascending; weights via scalar path
    #pragma unroll 1
    for (int cin = 0; cin < CIN_T; ++cin) {
      const float* wp = wTg + (size_t)(cb + cin) * 72;  // block-uniform
      float v[9];
      #pragma unroll
      for (int ky = 0; ky < 3; ++ky)
        #pragma unroll
        for (int kx = 0; kx < 3; ++kx)
          v[ky*3+kx] = s_in[buf][cin][(py+ky)*34 + px + kx];
      #pragma unroll
      for (int tp = 0; tp < 9; ++tp) {
        #pragma unroll
        for (int c = 0; c < 8; ++c)
          acc[tp][c] = __builtin_fmaf(v[tp], wp[tp*8+c], acc[tp][c]);
      }
    }
    buf ^= 1;
  }
#undef ISSUE
  // combine taps: row-major order, separate f32 adds; then bias, relu
  int y = ty + py, x0 = tx + px;
  #pragma unroll
  for (int c = 0; c < 8; ++c) {
    float tot = acc[0][c];
    #pragma unroll
    for (int tp = 1; tp < 9; ++tp) tot = __fadd_rn(tot, acc[tp][c]);
    tot = __fadd_rn(tot, bias[cob+c]);
    out[(size_t)(cob+c)*HW + y*H + x0] = fmaxf(tot, 0.f);
  }
}

// ------- 1x1 heads: k=256 single sequential FMA chain (verified) -----------
__global__ __launch_bounds__(256) void head_decode(
    const float* __restrict__ cfB, const float* __restrict__ rfC,
    const float* __restrict__ w_cls, const float* __restrict__ b_cls,
    const float* __restrict__ w_reg, const float* __restrict__ b_reg,
    const float* __restrict__ w_ctn, const float* __restrict__ b_ctn,
    float* __restrict__ score_all, int* __restrict__ label_all,
    float* __restrict__ box_all, u64* __restrict__ keys)
{
  __shared__ float s_ct[64];
  __shared__ float s_v[4][64];
  __shared__ int   s_i[4][64];
  int b = blockIdx.x;
  int lvl, lb;
  if (b < 256)      { lvl = 0; lb = b; }
  else if (b < 320) { lvl = 1; lb = b - 256; }
  else              { lvl = 2; lb = b - 320; }
  const int H  = (lvl==0)?128:(lvl==1)?64:32;
  const int HW = H*H;
  const int loff = (lvl==0)?0:(lvl==1)?16384:20480;
  const size_t foff = (lvl==0)?0:(lvl==1)?4194304:5242880;
  const float strd = (lvl==0)?8.f:(lvl==1)?16.f:32.f;
  const float* cf = cfB + foff;
  const float* rf = rfC + foff;
  int lane = threadIdx.x & 63;
  int wv = __builtin_amdgcn_readfirstlane((int)(threadIdx.x >> 6));  // SGPR
  int pix = lb*64 + lane;

  float lg[20];
  #pragma unroll
  for (int k = 0; k < 20; ++k) lg[k] = 0.f;
  float rg0 = 0.f, rg1 = 0.f, rg2 = 0.f, rg3 = 0.f, ct = 0.f;

  for (int c = 0; c < 256; ++c) {
    float fv = cf[(size_t)c*HW + pix];
    #pragma unroll
    for (int k = 0; k < 20; ++k)
      lg[k] = __builtin_fmaf(fv, w_cls[(wv*20+k)*256 + c], lg[k]);
    if (wv == 0) {
      float rv = rf[(size_t)c*HW + pix];
      rg0 = __builtin_fmaf(rv, w_reg[      c], rg0);
      rg1 = __builtin_fmaf(rv, w_reg[256 + c], rg1);
      rg2 = __builtin_fmaf(rv, w_reg[512 + c], rg2);
      rg3 = __builtin_fmaf(rv, w_reg[768 + c], rg3);
      ct  = __builtin_fmaf(rv, w_ctn[      c], ct);
    }
  }
  if (wv == 0) s_ct[lane] = __fadd_rn(ct, b_ctn[0]);
  __syncthreads();
  float sig_t = sig32(s_ct[lane]);

  // per-class f32 score, argmax with first-index tie-break
  float bsc = -1.f; int bk = 0;
  #pragma unroll
  for (int k = 0; k < 20; ++k) {
    float l32 = __fadd_rn(lg[k], b_cls[wv*20 + k]);
    float scv = sqrtf(__fmul_rn(sig32(l32), sig_t));
    if (scv > bsc) { bsc = scv; bk = wv*20 + k; }
  }
  s_v[wv][lane] = bsc;
  s_i[wv][lane] = bk;
  __syncthreads();
  if (wv != 0) return;
  #pragma unroll
  for (int g = 1; g < 4; ++g) {
    float v = s_v[g][lane];
    if (v > bsc) { bsc = v; bk = s_i[g][lane]; }
  }
  rg0 = __fadd_rn(rg0, b_reg[0]); rg1 = __fadd_rn(rg1, b_reg[1]);
  rg2 = __fadd_rn(rg2, b_reg[2]); rg3 = __fadd_rn(rg3, b_reg[3]);
  int yq = pix / H;
  int xq = pix - yq*H;
  float ax = (float)xq + 0.5f, ay = (float)yq + 0.5f;
  float e0 = (float)exp((double)rg0), e1 = (float)exp((double)rg1);
  float e2 = (float)exp((double)rg2), e3 = (float)exp((double)rg3);
  float scl = strd * (1.0f/1024.0f);
  float bx1 = fminf(fmaxf(__fmul_rn(__fadd_rn(ax, -e0), scl), 0.f), 1.f);
  float by1 = fminf(fmaxf(__fmul_rn(__fadd_rn(ay, -e1), scl), 0.f), 1.f);
  float bx2 = fminf(fmaxf(__fmul_rn(__fadd_rn(ax,  e2), scl), 0.f), 1.f);
  float by2 = fminf(fmaxf(__fmul_rn(__fadd_rn(ay,  e3), scl), 0.f), 1.f);
  int gi = loff + pix;
  score_all[gi] = bsc;
  label_all[gi] = bk;
  box_all[gi*4+0] = bx1; box_all[gi*4+1] = by1;
  box_all[gi*4+2] = bx2; box_all[gi*4+3] = by2;
  keys[gi] = ((u64)fmono(bsc) << 32) | (u64)(0xFFFFFFFFu - (u32)pix);
}

// ---------------- bitonic sort (descending, u64 keys) ----------------------
__global__ __launch_bounds__(256) void sort_local(u64* __restrict__ keys)
{
  __shared__ u64 s[2048];
  int t = threadIdx.x;
  int base = blockIdx.x * 2048;
  #pragma unroll
  for (int r = 0; r < 8; ++r) s[t + r*256] = keys[base + t + r*256];
  __syncthreads();
  for (int k = 2; k <= 2048; k <<= 1) {
    for (int j = k >> 1; j >= 1; j >>= 1) {
      #pragma unroll
      for (int r = 0; r < 4; ++r) {
        int p = t + r*256;
        int i = ((p & ~(j-1)) << 1) | (p & (j-1));
        bool asc = (((base + i) & k) != 0);
        u64 a = s[i], b2 = s[i|j];
        if (asc ? (a > b2) : (a < b2)) { s[i] = b2; s[i|j] = a; }
      }
      __syncthreads();
    }
  }
  #pragma unroll
  for (int r = 0; r < 8; ++r) keys[base + t + r*256] = s[t + r*256];
}

__global__ void sort_global_pass(u64* __restrict__ keys, int j, int k, int P)
{
  int p = blockIdx.x*256 + threadIdx.x;
  if (p >= (P >> 1)) return;
  int i = ((p & ~(j-1)) << 1) | (p & (j-1));
  int l = i | j;
  bool asc = ((i & k) != 0);
  u64 a = keys[i], b = keys[l];
  if (asc ? (a > b) : (a < b)) { keys[i] = b; keys[l] = a; }
}

__global__ __launch_bounds__(256) void sort_local_finish(u64* __restrict__ keys, int k)
{
  __shared__ u64 s[2048];
  int t = threadIdx.x;
  int base = blockIdx.x * 2048;
  #pragma unroll
  for (int r = 0; r < 8; ++r) s[t + r*256] = keys[base + t + r*256];
  __syncthreads();
  for (int j = 1024; j >= 1; j >>= 1) {
    #pragma unroll
    for (int r = 0; r < 4; ++r) {
      int p = t + r*256;
      int i = ((p & ~(j-1)) << 1) | (p & (j-1));
      bool asc = (((base + i) & k) != 0);
      u64 a = s[i], b2 = s[i|j];
      if (asc ? (a > b2) : (a < b2)) { s[i] = b2; s[i|j] = a; }
    }
    __syncthreads();
  }
  #pragma unroll
  for (int r = 0; r < 8; ++r) keys[base + t + r*256] = s[t + r*256];
}

__global__ void zero_keys(u64* __restrict__ keys, int n) {
  int i = blockIdx.x*256 + threadIdx.x;
  if (i < n) keys[i] = 0ull;
}

// ---------------- gather per-level top-1000 --------------------------------
__global__ void gather_top(const u64* __restrict__ keys,
    const float* __restrict__ score_all, const int* __restrict__ label_all,
    const float* __restrict__ box_all, int loff, int lvl,
    float* __restrict__ out, float* __restrict__ s3k, int* __restrict__ l3k,
    float* __restrict__ b3k)
{
  int r = blockIdx.x*256 + threadIdx.x;
  if (r >= 1000) return;
  u64 key = keys[r];
  u32 pix = 0xFFFFFFFFu - (u32)(key & 0xFFFFFFFFull);
  int gi = loff + (int)pix;
  int g = lvl*1000 + r;
  float sc = score_all[gi];
  int lb = label_all[gi];
  s3k[g] = sc; l3k[g] = lb;
  out[12000 + g] = sc;
  out[15000 + g] = (float)lb;
  #pragma unroll
  for (int c = 0; c < 4; ++c) {
    float v = box_all[gi*4 + c];
    b3k[g*4+c] = v;
    out[g*4+c] = v;
  }
}

// ---------------- NMS ------------------------------------------------------
__global__ void nms_pack(const float* __restrict__ s3k, u64* __restrict__ nkeys) {
  int r = blockIdx.x*256 + threadIdx.x;
  if (r >= 4096) return;
  nkeys[r] = (r < 3000)
      ? (((u64)fmono(s3k[r]) << 32) | (u64)(0xFFFFFFFFu - (u32)r))
      : 0ull;
}

__global__ void nms_gather(const u64* __restrict__ nkeys,
    const float* __restrict__ s3k, const int* __restrict__ l3k, const float* __restrict__ b3k,
    float* __restrict__ bs, int* __restrict__ ls, int* __restrict__ order,
    float* __restrict__ ss)
{
  int i = blockIdx.x*256 + threadIdx.x;
  if (i >= 3000) return;
  u64 key = nkeys[i];
  u32 r = 0xFFFFFFFFu - (u32)(key & 0xFFFFFFFFull);
  order[i] = (int)r;
  ss[i] = s3k[r];
  ls[i] = l3k[r];
  #pragma unroll
  for (int c = 0; c < 4; ++c) bs[i*4+c] = b3k[(int)r*4+c];
}

__global__ void nms_supp(const float* __restrict__ bs, const int* __restrict__ ls,
                         u64* __restrict__ supp)
{
  int id = blockIdx.x*256 + threadIdx.x;
  if (id >= 3000*47) return;
  int i = id / 47, w = id - (id/47)*47;
  float x1 = bs[i*4+0], y1 = bs[i*4+1], x2 = bs[i*4+2], y2 = bs[i*4+3];
  float ai = (x2-x1)*(y2-y1);
  int li = ls[i];
  u64 m = 0;
  int j0 = w*64;
  #pragma unroll 1
  for (int bb = 0; bb < 64; ++bb) {
    int j = j0 + bb;
    if (j >= 3000) break;
    if (j <= i || ls[j] != li) continue;
    float xj1 = bs[j*4+0], yj1 = bs[j*4+1], xj2 = bs[j*4+2], yj2 = bs[j*4+3];
    float aj = (xj2-xj1)*(yj2-yj1);
    float xx1 = fmaxf(x1, xj1), yy1 = fmaxf(y1, yj1);
    float xx2 = fminf(x2, xj2), yy2 = fminf(y2, yj2);
    float inter = fmaxf(1e-28f, xx2-xx1) * fmaxf(1e-28f, yy2-yy1);
    float iou = inter / (ai + aj - inter + 1e-14f);
    if (iou > 0.6f) m |= (1ull << bb);
  }
  supp[(size_t)i*47 + w] = m;
}

// serial greedy scan, latency-hidden: depth-64 register prefetch ring +
// scalar (readlane) current-word bit test. One wave. (r14 version, verified)
__global__ __launch_bounds__(64) void nms_seq(const u64* __restrict__ supp,
    const float* __restrict__ ss, const int* __restrict__ order,
    float* __restrict__ out)
{
  int lane = threadIdx.x;  // 64 threads, one wave
  bool active = lane < 47;
  u64 kw = 0;
  if (active) {
    for (int bb = 0; bb < 64; ++bb) {
      int i = lane*64 + bb;
      if (i < 3000 && ss[i] >= CONF) kw |= (1ull << bb);
    }
  }
  u64 ring[64];
  #pragma unroll
  for (int d = 0; d < 64; ++d)
    ring[d] = active ? supp[(size_t)d*47 + lane] : 0ull;

  #pragma unroll 1
  for (int blk = 0; blk < 47; ++blk) {
    #pragma unroll
    for (int d = 0; d < 64; ++d) {
      u32 half = (d < 32)
          ? __builtin_amdgcn_readlane((u32)kw, blk)
          : __builtin_amdgcn_readlane((u32)(kw >> 32), blk);
      if ((half >> (d & 31)) & 1u)
        kw &= ~ring[d];
      int nr = (blk + 1) * 64 + d;
      ring[d] = (active && nr < 3008) ? supp[(size_t)nr*47 + lane] : 0ull;
    }
  }
  if (active) {
    for (int bb = 0; bb < 64; ++bb) {
      int i = lane*64 + bb;
      if (i < 3000) out[18000 + order[i]] = ((kw >> bb) & 1ull) ? 1.0f : 0.0f;
    }
  }
}

// ---------------- host -----------------------------------------------------
extern "C" void kernel_launch(void* const* d_in, const int* in_sizes, int n_in,
                              void* d_out, int out_size, void* d_ws, size_t ws_size,
                              hipStream_t stream)
{
  const float* p3    = (const float*)d_in[0];
  const float* p4    = (const float*)d_in[1];
  const float* p5    = (const float*)d_in[2];
  const float* cls_w = (const float*)d_in[3];
  const float* cls_b = (const float*)d_in[4];
  const float* reg_w = (const float*)d_in[5];
  const float* reg_b = (const float*)d_in[6];
  const float* w_cls = (const float*)d_in[7];
  const float* b_cls = (const float*)d_in[8];
  const float* w_reg = (const float*)d_in[9];
  const float* b_reg = (const float*)d_in[10];
  const float* w_ctn = (const float*)d_in[11];
  const float* b_ctn = (const float*)d_in[12];
  float* out = (float*)d_out;

  char* wsb = (char*)d_ws;
  size_t off = 0;
  auto alloc = [&](size_t bytes) -> void* {
    void* p = wsb + off;
    off = (off + bytes + 255) & ~(size_t)255;
    return p;
  };
  const size_t SLAB = 5505024;  // floats: 256*(16384+4096+1024)
  float* A = (float*)alloc(SLAB*4);
  float* B = (float*)alloc(SLAB*4);
  float* C = (float*)alloc(SLAB*4);
  float* D = (float*)alloc(SLAB*4);
  float* wT_cls = (float*)alloc((size_t)2359296*4);
  float* wT_reg = (float*)alloc((size_t)2359296*4);
  float* zbuf = (float*)alloc(2048);
  float* score_all = (float*)alloc(21504*4);
  int*   label_all = (int*)alloc(21504*4);
  float* box_all   = (float*)alloc(21504*16);
  u64*   keys      = (u64*)alloc(22528*8);
  float* s3k  = (float*)alloc(3000*4);
  int*   l3k  = (int*)alloc(3000*4);
  float* b3k  = (float*)alloc(12000*4);
  u64*   nkeys = (u64*)alloc(4096*8);
  float* bs   = (float*)alloc(12000*4);
  int*   ls   = (int*)alloc(3000*4);
  int*   order= (int*)alloc(3000*4);
  float* ss   = (float*)alloc(3000*4);
  u64*   supp = (u64*)alloc((size_t)141376*8);  // 3008 rows x 47 (ring pad)

  const size_t F1 = 4194304, F2 = 5242880;
  const size_t WTL = 589824;  // per-layer transposed-weight float count

  // zero the async-staging clamp buffer, then pre-transpose weights
  zero_keys<<<dim3(1), dim3(256), 0, stream>>>((u64*)zbuf, 256);
  wtrans<<<dim3(9216), dim3(256), 0, stream>>>(cls_w, wT_cls, 2359296);
  wtrans<<<dim3(9216), dim3(256), 0, stream>>>(reg_w, wT_reg, 2359296);

  // merged dual-tower conv dispatches (4 layers, 5376 blocks each)
  auto CV2 = [&](const float* ic, const float* ir, float* oc, float* orr,
                 int layer) {
    conv_all<<<dim3(5376), dim3(256), 0, stream>>>(
        ic, ic+F1, ic+F2, ir, ir+F1, ir+F2,
        oc, oc+F1, oc+F2, orr, orr+F1, orr+F2,
        wT_cls + layer*WTL, wT_reg + layer*WTL,
        cls_b + layer*256, reg_b + layer*256, zbuf);
  };
  // layer 0 reads the raw pyramid (non-contiguous p3/p4/p5)
  conv_all<<<dim3(5376), dim3(256), 0, stream>>>(
      p3, p4, p5, p3, p4, p5,
      A, A+F1, A+F2, C, C+F1, C+F2,
      wT_cls, wT_reg, cls_b, reg_b, zbuf);
  CV2(A, C, B, D, 1);
  CV2(B, D, A, C, 2);
  CV2(A, C, B, D, 3);
  // cf = B, rf = D

  zero_keys<<<dim3(4), dim3(256), 0, stream>>>(keys + 21504, 1024);
  head_decode<<<dim3(336), dim3(256), 0, stream>>>(B, D, w_cls, b_cls, w_reg, b_reg,
      w_ctn, b_ctn, score_all, label_all, box_all, keys);

  auto sortP = [&](u64* k0, int P) {
    sort_local<<<dim3(P/2048), dim3(256), 0, stream>>>(k0);
    for (int k = 4096; k <= P; k <<= 1) {
      for (int j = k >> 1; j >= 2048; j >>= 1)
        sort_global_pass<<<dim3((P/2 + 255)/256), dim3(256), 0, stream>>>(k0, j, k, P);
      sort_local_finish<<<dim3(P/2048), dim3(256), 0, stream>>>(k0, k);
    }
  };
  sortP(keys,        16384);
  sortP(keys+16384,  4096);
  sortP(keys+20480,  2048);

  const int LOFF[3] = {0, 16384, 20480};
  for (int lvl = 0; lvl < 3; ++lvl)
    gather_top<<<dim3(4), dim3(256), 0, stream>>>(keys + LOFF[lvl], score_all,
        label_all, box_all, LOFF[lvl], lvl, out, s3k, l3k, b3k);

  nms_pack<<<dim3(16), dim3(256), 0, stream>>>(s3k, nkeys);
  sortP(nkeys, 4096);
  nms_gather<<<dim3(12), dim3(256), 0, stream>>>(nkeys, s3k, l3k, b3k, bs, ls, order, ss);
  nms_supp<<<dim3((3000*47 + 255)/256), dim3(256), 0, stream>>>(bs, ls, supp);
  nms_seq<<<dim3(1), dim3(64), 0, stream>>>(supp, ss, order, out);
}